// Round 9
// baseline (147.689 us; speedup 1.0000x reference)
//
#include <hip/hip_runtime.h>
#include <cstdint>
#include <cstddef>

// ---------- types ----------
typedef __attribute__((ext_vector_type(8))) __bf16 bf16x8;
typedef __attribute__((ext_vector_type(4))) float f32x4;

// fp32 -> bf16 round-to-nearest-even (manual; used where vector cvt isn't natural)
__device__ __forceinline__ unsigned short f2bf(float x) {
    unsigned int u = __float_as_uint(x);
    u += 0x7fffu + ((u >> 16) & 1u);
    return (unsigned short)(u >> 16);
}

__device__ __forceinline__ ushort4 pack4bf(float a, float b, float c, float d) {
    union { ushort4 v; __bf16 e[4]; } u;
    u.e[0] = (__bf16)a; u.e[1] = (__bf16)b; u.e[2] = (__bf16)c; u.e[3] = (__bf16)d;
    return u.v;
}

typedef const __attribute__((address_space(1))) void* gptr_t;
typedef __attribute__((address_space(3))) void* lptr_t;
__device__ __forceinline__ void gload_lds16(const void* g, void* l) {
    __builtin_amdgcn_global_load_lds((gptr_t)g, (lptr_t)l, 16, 0, 0);
}

// ---------- fused tiled transpose+cast of the 4 weight matrices ----------
__global__ __launch_bounds__(256) void transpose4_kernel(const float* __restrict__ W0,
                                                         const float* __restrict__ W1,
                                                         const float* __restrict__ W2,
                                                         const float* __restrict__ W3,
                                                         unsigned short* __restrict__ T0,
                                                         unsigned short* __restrict__ T1,
                                                         unsigned short* __restrict__ T2,
                                                         unsigned short* __restrict__ T3,
                                                         float s0) {
    __shared__ float Ts[64][65];
    const int D = 1024;
    const int m = blockIdx.z;
    const float* W = (m == 0) ? W0 : (m == 1) ? W1 : (m == 2) ? W2 : W3;
    unsigned short* T = (m == 0) ? T0 : (m == 1) ? T1 : (m == 2) ? T2 : T3;
    const float scale = (m == 0) ? s0 : 1.0f;
    const int kt = blockIdx.y * 64, nt = blockIdx.x * 64;
    const int tid = threadIdx.x;

    {
        const int r = tid >> 2, cs = (tid & 3) * 16;
#pragma unroll
        for (int j = 0; j < 16; j += 4) {
            f32x4 v = *(const f32x4*)&W[(size_t)(kt + r) * D + nt + cs + j];
#pragma unroll
            for (int e = 0; e < 4; ++e) Ts[r][cs + j + e] = v[e];
        }
    }
    __syncthreads();
    {
        const int n = tid >> 2, ks = (tid & 3) * 16;
        union { bf16x8 v[2]; __bf16 e[16]; } cv;
#pragma unroll
        for (int j = 0; j < 16; ++j) cv.e[j] = (__bf16)(Ts[ks + j][n] * scale);
        *(bf16x8*)&T[(size_t)(nt + n) * D + kt + ks] = cv.v[0];
        *(bf16x8*)&T[(size_t)(nt + n) * D + kt + ks + 8] = cv.v[1];
    }
}

// ---------- GEMM, C = A * B with Bt = B^T given ----------
template <int AF32, int OUTBF>
__global__ __launch_bounds__(256) void gemm_bt(const void* __restrict__ Ain,
                                               const unsigned short* __restrict__ Bt,
                                               void* __restrict__ Cout,
                                               int M, int N, int K, int lda, int ldc,
                                               int nbx) {
    __shared__ __align__(16) unsigned short Au[128 * 32];
    __shared__ __align__(16) unsigned short Bs[128 * 32];
    const int tid = threadIdx.x;
    const int w = tid >> 6;
    const int lane = tid & 63;

    const int nwg = gridDim.x;
    const int q8 = nwg >> 3;
    const int orig = blockIdx.x;
    const int newlin = (orig & 7) * q8 + (orig >> 3);
    const int by = newlin / nbx;
    const int bx = newlin - by * nbx;
    const int m0 = by * 128;
    const int n0 = bx * 128;
    const int wr = w >> 1, wc = w & 1;

    f32x4 acc[4][4];
#pragma unroll
    for (int i = 0; i < 4; ++i)
#pragma unroll
        for (int j = 0; j < 4; ++j) acc[i][j] = f32x4{0.f, 0.f, 0.f, 0.f};

    const int arow = tid >> 1;
    const int akh = tid & 1;
    const float* A32 = (const float*)Ain;
    f32x4 ar[4];
    if (AF32) {
        const float* s = A32 + (size_t)(m0 + arow) * lda + akh * 16;
#pragma unroll
        for (int j = 0; j < 4; ++j) ar[j] = *(const f32x4*)(s + j * 4);
    }

    for (int kt = 0; kt < K; kt += 32) {
        if (AF32) {
            union { bf16x8 v[2]; __bf16 e[16]; } cv;
#pragma unroll
            for (int j = 0; j < 16; ++j) cv.e[j] = (__bf16)ar[j >> 2][j & 3];
            *(bf16x8*)&Au[arow * 32 + akh * 16] = cv.v[0];
            *(bf16x8*)&Au[arow * 32 + akh * 16 + 8] = cv.v[1];
        } else {
            const unsigned short* A = (const unsigned short*)Ain;
#pragma unroll
            for (int p = 0; p < 2; ++p) {
                int c = p * 4 + w;
                int row = c * 16 + (lane >> 2);
                gload_lds16(A + (size_t)(m0 + row) * lda + kt + (lane & 3) * 8,
                            &Au[c * 512]);
            }
        }
#pragma unroll
        for (int p = 0; p < 2; ++p) {
            int c = p * 4 + w;
            int row = c * 16 + (lane >> 2);
            gload_lds16(Bt + (size_t)(n0 + row) * K + kt + (lane & 3) * 8,
                        &Bs[c * 512]);
        }
        __syncthreads();

        if (AF32 && kt + 32 < K) {
            const float* s = A32 + (size_t)(m0 + arow) * lda + kt + 32 + akh * 16;
#pragma unroll
            for (int j = 0; j < 4; ++j) ar[j] = *(const f32x4*)(s + j * 4);
        }

        bf16x8 af[4], bfr[4];
#pragma unroll
        for (int m = 0; m < 4; ++m)
            af[m] = *(const bf16x8*)&Au[(wr * 64 + m * 16 + (lane & 15)) * 32 +
                                        (lane >> 4) * 8];
#pragma unroll
        for (int n = 0; n < 4; ++n)
            bfr[n] = *(const bf16x8*)&Bs[(wc * 64 + n * 16 + (lane & 15)) * 32 +
                                         (lane >> 4) * 8];
#pragma unroll
        for (int m = 0; m < 4; ++m)
#pragma unroll
            for (int n = 0; n < 4; ++n)
                acc[m][n] = __builtin_amdgcn_mfma_f32_16x16x32_bf16(af[m], bfr[n], acc[m][n], 0, 0, 0);
        __syncthreads();
    }

    const int crow = (lane >> 4) * 4;
    const int ccol = lane & 15;
#pragma unroll
    for (int m = 0; m < 4; ++m) {
#pragma unroll
        for (int n = 0; n < 4; ++n) {
            int r0 = m0 + wr * 64 + m * 16 + crow;
            int c0 = n0 + wc * 64 + n * 16 + ccol;
#pragma unroll
            for (int j = 0; j < 4; ++j) {
                if (OUTBF)
                    ((unsigned short*)Cout)[(size_t)(r0 + j) * ldc + c0] = f2bf(acc[m][n][j]);
                else
                    ((float*)Cout)[(size_t)(r0 + j) * ldc + c0] = acc[m][n][j];
            }
        }
    }
}

// ---------- causal flash attention (swapped-operand, 32 q per wave) ----------
// QKV fused [B*L, 3072] bf16: Q cols [0,1024), K [1024,2048), V [2048,3072).
// Q pre-scaled by log2(e)/sqrt(hd). O written in-place over Q columns.
// Grid (32 bh, 16 qblk128): linear%8 = bh%8 -> one head per XCD L2.
// y -> qblk 15-y: heavy blocks dispatch first. Block = 128 q rows; each wave
// owns 32 q (2 halves of 16). K-fragment reads, V-fragment reads, and staging
// are shared across both halves -> 2x MFMA per LDS/staging op vs r7.
// Per wave exactly one diagonal-masked tile (its last active tile); waves 0/1
// skip compute (not staging/barriers) on the block's final tile.
__global__ __launch_bounds__(256) void flash_kernel(unsigned short* __restrict__ QKV) {
    __shared__ __align__(16) unsigned short Ks[2][64 * 72];     // [kv][d], +8 pad
    __shared__ __align__(16) unsigned short Vs[2][64 * 72];     // [d][kv], kv XOR-swizzled
    __shared__ __align__(16) unsigned short Ps[4][2][16 * 72];  // per-wave, per-half P^T [q][kv]

    const int tid = threadIdx.x;
    const int w = tid >> 6;
    const int lane = tid & 63;
    const int bh = blockIdx.x;          // 0..31 ; XCD = bh % 8
    const int b = bh >> 4, h = bh & 15;
    const int rowbase = b * 2048;
    const int hd0 = h * 64;
    const int S = 3072;

    const int sr = tid >> 3;            // staging: K/V rows {p*32+sr}
    const int sc = (tid & 7) * 8;       //          cols [sc, sc+8)
    const int vswz = (tid & 7) << 3;    // V store column swizzle

    const int qi = lane & 15;           // lane's q column within a half
    const int g = lane >> 4;            // lane group

    const int qblk = (15 - (int)blockIdx.y) * 128;
    const int q0 = qblk + w * 32;       // wave's first q row
    const int nt = qblk / 64 + 2;

    // Q fragments (B-operand): [half][d-step]
    bf16x8 qf[2][2];
#pragma unroll
    for (int half = 0; half < 2; ++half)
#pragma unroll
        for (int st = 0; st < 2; ++st)
            qf[half][st] = *(const bf16x8*)(QKV + (size_t)(rowbase + q0 + half * 16 + qi) * S +
                                            hd0 + st * 32 + g * 8);

    float m_prev[2] = {-1e30f, -1e30f}, lsum[2] = {0.f, 0.f};
    f32x4 oacc[2][4];
#pragma unroll
    for (int half = 0; half < 2; ++half)
#pragma unroll
        for (int n = 0; n < 4; ++n) oacc[half][n] = f32x4{0.f, 0.f, 0.f, 0.f};

    bf16x8 kreg[2], vreg[2];
    // prologue: tile 0 -> regs -> buf0 ; tile 1 -> regs (nt >= 2 always)
#pragma unroll
    for (int p = 0; p < 2; ++p) {
        size_t gi = (size_t)(rowbase + p * 32 + sr) * S + hd0 + sc;
        kreg[p] = *(const bf16x8*)(QKV + gi + 1024);
        vreg[p] = *(const bf16x8*)(QKV + gi + 2048);
    }
#pragma unroll
    for (int p = 0; p < 2; ++p) {
        int r = p * 32 + sr;
        *(bf16x8*)&Ks[0][r * 72 + sc] = kreg[p];
        int rs = r ^ vswz;
#pragma unroll
        for (int jj = 0; jj < 8; ++jj)
            Vs[0][(sc + jj) * 72 + rs] = ((const unsigned short*)&vreg[p])[jj];
    }
#pragma unroll
    for (int p = 0; p < 2; ++p) {
        size_t gi = (size_t)(rowbase + 64 + p * 32 + sr) * S + hd0 + sc;
        kreg[p] = *(const bf16x8*)(QKV + gi + 1024);
        vreg[p] = *(const bf16x8*)(QKV + gi + 2048);
    }
    __syncthreads();

    int cur = 0;
    for (int t = 0; t < nt; ++t) {
        const int kv0 = t * 64;
        // ---- write staged regs (tile t+1) to the other buffer; issue t+2 loads ----
        if (t + 1 < nt) {
#pragma unroll
            for (int p = 0; p < 2; ++p) {
                int r = p * 32 + sr;
                *(bf16x8*)&Ks[cur ^ 1][r * 72 + sc] = kreg[p];
                int rs = r ^ vswz;
#pragma unroll
                for (int jj = 0; jj < 8; ++jj)
                    Vs[cur ^ 1][(sc + jj) * 72 + rs] = ((const unsigned short*)&vreg[p])[jj];
            }
            if (t + 2 < nt) {
#pragma unroll
                for (int p = 0; p < 2; ++p) {
                    size_t gi = (size_t)(rowbase + (t + 2) * 64 + p * 32 + sr) * S + hd0 + sc;
                    kreg[p] = *(const bf16x8*)(QKV + gi + 1024);
                    vreg[p] = *(const bf16x8*)(QKV + gi + 2048);
                }
            }
        }

        // does this tile intersect this wave's causal range?
        const bool act = (kv0 <= qblk + w * 32 + 31);
        if (act) {
            const unsigned short* Kc = Ks[cur];
            const unsigned short* Vc = Vs[cur];

            // ---- S^T = K Q^T, both halves share the K fragments ----
            f32x4 sacc[2][4];
            __builtin_amdgcn_s_setprio(1);
#pragma unroll
            for (int n = 0; n < 4; ++n) {
                bf16x8 k0 = *(const bf16x8*)&Kc[(n * 16 + qi) * 72 + g * 8];
                bf16x8 k1 = *(const bf16x8*)&Kc[(n * 16 + qi) * 72 + 32 + g * 8];
#pragma unroll
                for (int half = 0; half < 2; ++half) {
                    f32x4 c = f32x4{0.f, 0.f, 0.f, 0.f};
                    c = __builtin_amdgcn_mfma_f32_16x16x32_bf16(k0, qf[half][0], c, 0, 0, 0);
                    c = __builtin_amdgcn_mfma_f32_16x16x32_bf16(k1, qf[half][1], c, 0, 0, 0);
                    sacc[half][n] = c;
                }
            }
            __builtin_amdgcn_s_setprio(0);

            // ---- online softmax (per half), exp2 domain, lane-local column ----
            const bool diag = (kv0 + 64 > qblk + w * 32);
#pragma unroll
            for (int half = 0; half < 2; ++half) {
                if (diag) {
                    const int lim = qblk + w * 32 + half * 16 + qi - kv0;
#pragma unroll
                    for (int n = 0; n < 4; ++n)
#pragma unroll
                        for (int j = 0; j < 4; ++j)
                            if (n * 16 + g * 4 + j > lim) sacc[half][n][j] = -1e30f;
                }
                float tmax = -1e30f;
#pragma unroll
                for (int n = 0; n < 4; ++n) {
                    float a = fmaxf(fmaxf(sacc[half][n][0], sacc[half][n][1]),
                                    fmaxf(sacc[half][n][2], sacc[half][n][3]));
                    tmax = fmaxf(tmax, a);
                }
                tmax = fmaxf(tmax, __shfl_xor(tmax, 16));
                tmax = fmaxf(tmax, __shfl_xor(tmax, 32));

                const bool defer = __all(tmax - m_prev[half] <= 8.0f);
                const float mnew = defer ? m_prev[half] : fmaxf(m_prev[half], tmax);

                float psum = 0.f;
#pragma unroll
                for (int n = 0; n < 4; ++n) {
                    float p0 = exp2f(sacc[half][n][0] - mnew);
                    float p1 = exp2f(sacc[half][n][1] - mnew);
                    float p2 = exp2f(sacc[half][n][2] - mnew);
                    float p3 = exp2f(sacc[half][n][3] - mnew);
                    psum += (p0 + p1) + (p2 + p3);
                    *(ushort4*)&Ps[w][half][qi * 72 + n * 16 + g * 4] = pack4bf(p0, p1, p2, p3);
                }
                psum += __shfl_xor(psum, 16);
                psum += __shfl_xor(psum, 32);
                if (!defer) {
                    float alpha = exp2f(m_prev[half] - mnew);
                    lsum[half] *= alpha;
#pragma unroll
                    for (int n = 0; n < 4; ++n)
#pragma unroll
                        for (int j = 0; j < 4; ++j) oacc[half][n][j] *= alpha;
                    m_prev[half] = mnew;
                }
                lsum[half] += psum;
            }

            // compile-time fence: Ps writes must precede the reads below
            asm volatile("" ::: "memory");

            // ---- O^T += V^T P^T, V fragments shared across halves ----
            __builtin_amdgcn_s_setprio(1);
#pragma unroll
            for (int st = 0; st < 2; ++st) {
                bf16x8 pt0 = *(const bf16x8*)&Ps[w][0][qi * 72 + st * 32 + g * 8];
                bf16x8 pt1 = *(const bf16x8*)&Ps[w][1][qi * 72 + st * 32 + g * 8];
#pragma unroll
                for (int n = 0; n < 4; ++n) {
                    int d = n * 16 + qi;
                    int o = (st * 32 + g * 8) ^ (((d >> 3) & 7) << 3);
                    bf16x8 vfr = *(const bf16x8*)&Vc[d * 72 + o];
                    oacc[0][n] = __builtin_amdgcn_mfma_f32_16x16x32_bf16(vfr, pt0, oacc[0][n], 0, 0, 0);
                    oacc[1][n] = __builtin_amdgcn_mfma_f32_16x16x32_bf16(vfr, pt1, oacc[1][n], 0, 0, 0);
                }
            }
            __builtin_amdgcn_s_setprio(0);
        }
        __syncthreads();
        cur ^= 1;
    }

    // ---- normalize, transpose via Ps, coalesced O write over own Q rows ----
    {
#pragma unroll
        for (int half = 0; half < 2; ++half) {
            float inv = 1.0f / lsum[half];   // qi-space; O^T col = qi -> direct
#pragma unroll
            for (int n = 0; n < 4; ++n)
                *(ushort4*)&Ps[w][half][qi * 72 + n * 16 + g * 4] =
                    pack4bf(oacc[half][n][0] * inv, oacc[half][n][1] * inv,
                            oacc[half][n][2] * inv, oacc[half][n][3] * inv);
        }
        asm volatile("" ::: "memory");
        const int r = lane >> 2;             // q row 0..15 within half
        const int cs = (lane & 3) * 16;      // d start
#pragma unroll
        for (int half = 0; half < 2; ++half) {
            bf16x8 o0 = *(const bf16x8*)&Ps[w][half][r * 72 + cs];
            bf16x8 o1 = *(const bf16x8*)&Ps[w][half][r * 72 + cs + 8];
            unsigned short* dst = &QKV[(size_t)(rowbase + q0 + half * 16 + r) * S + hd0 + cs];
            *(bf16x8*)&dst[0] = o0;
            *(bf16x8*)&dst[8] = o1;
        }
    }
}

// ---------- launch ----------
extern "C" void kernel_launch(void* const* d_in, const int* in_sizes, int n_in,
                              void* d_out, int out_size, void* d_ws, size_t ws_size,
                              hipStream_t stream) {
    const float* x  = (const float*)d_in[0];
    const float* Wq = (const float*)d_in[1];
    const float* Wk = (const float*)d_in[2];
    const float* Wv = (const float*)d_in[3];
    const float* Wo = (const float*)d_in[4];
    float* out = (float*)d_out;

    const int WN = 1024 * 1024;

    // workspace: Wqkv_t [3072][1024] (6MB) + Wo_t (2MB) + QKV [4096][3072] (24MB) = 32MB
    unsigned short* ws   = (unsigned short*)d_ws;
    unsigned short* Wqkv = ws;
    unsigned short* Wot  = Wqkv + 3 * WN;
    unsigned short* QKV  = Wot + WN;

    // Q scale: 1/sqrt(64) * log2(e)  (softmax in exp2 domain)
    transpose4_kernel<<<dim3(16, 16, 4), 256, 0, stream>>>(
        Wq, Wk, Wv, Wo, Wqkv, Wqkv + WN, Wqkv + 2 * WN, Wot, 0.125f * 1.4426950408889634f);

    // fused QKV projection: [4096,1024] x [1024,3072] -> [4096,3072]
    gemm_bt<1, 1><<<24 * 32, 256, 0, stream>>>(
        x, Wqkv, QKV, 4096, 3072, 1024, 1024, 3072, 24);

    flash_kernel<<<dim3(32, 16), 256, 0, stream>>>(QKV);

    // output projection: A = O (bf16, Q region of QKV, lda=3072)
    gemm_bt<0, 0><<<8 * 32, 256, 0, stream>>>(
        QKV, Wot, out, 4096, 1024, 1024, 3072, 1024, 8);
}

// Round 10
// 131.209 us; speedup vs baseline: 1.1256x; 1.1256x over previous
//
#include <hip/hip_runtime.h>
#include <cstdint>
#include <cstddef>

// ---------- types ----------
typedef __attribute__((ext_vector_type(8))) __bf16 bf16x8;
typedef __attribute__((ext_vector_type(4))) float f32x4;

// fp32 -> bf16 round-to-nearest-even (manual; used where vector cvt isn't natural)
__device__ __forceinline__ unsigned short f2bf(float x) {
    unsigned int u = __float_as_uint(x);
    u += 0x7fffu + ((u >> 16) & 1u);
    return (unsigned short)(u >> 16);
}

__device__ __forceinline__ ushort4 pack4bf(float a, float b, float c, float d) {
    union { ushort4 v; __bf16 e[4]; } u;
    u.e[0] = (__bf16)a; u.e[1] = (__bf16)b; u.e[2] = (__bf16)c; u.e[3] = (__bf16)d;
    return u.v;
}

typedef const __attribute__((address_space(1))) void* gptr_t;
typedef __attribute__((address_space(3))) void* lptr_t;
__device__ __forceinline__ void gload_lds16(const void* g, void* l) {
    __builtin_amdgcn_global_load_lds((gptr_t)g, (lptr_t)l, 16, 0, 0);
}

// ---------- cast x (fp32 -> bf16), 4 elems/thread, into d_out scratch ----------
__global__ __launch_bounds__(256) void cast_x_kernel(const float* __restrict__ x,
                                                     unsigned short* __restrict__ out) {
    int i = blockIdx.x * 256 + threadIdx.x;
    float4 v = ((const float4*)x)[i];
    ushort4 o;
    o.x = f2bf(v.x); o.y = f2bf(v.y); o.z = f2bf(v.z); o.w = f2bf(v.w);
    ((ushort4*)out)[i] = o;
}

// ---------- fused tiled transpose+cast of the 4 weight matrices ----------
__global__ __launch_bounds__(256) void transpose4_kernel(const float* __restrict__ W0,
                                                         const float* __restrict__ W1,
                                                         const float* __restrict__ W2,
                                                         const float* __restrict__ W3,
                                                         unsigned short* __restrict__ T0,
                                                         unsigned short* __restrict__ T1,
                                                         unsigned short* __restrict__ T2,
                                                         unsigned short* __restrict__ T3,
                                                         float s0) {
    __shared__ float Ts[64][65];
    const int D = 1024;
    const int m = blockIdx.z;
    const float* W = (m == 0) ? W0 : (m == 1) ? W1 : (m == 2) ? W2 : W3;
    unsigned short* T = (m == 0) ? T0 : (m == 1) ? T1 : (m == 2) ? T2 : T3;
    const float scale = (m == 0) ? s0 : 1.0f;
    const int kt = blockIdx.y * 64, nt = blockIdx.x * 64;
    const int tid = threadIdx.x;

    {
        const int r = tid >> 2, cs = (tid & 3) * 16;
#pragma unroll
        for (int j = 0; j < 16; j += 4) {
            f32x4 v = *(const f32x4*)&W[(size_t)(kt + r) * D + nt + cs + j];
#pragma unroll
            for (int e = 0; e < 4; ++e) Ts[r][cs + j + e] = v[e];
        }
    }
    __syncthreads();
    {
        const int n = tid >> 2, ks = (tid & 3) * 16;
        union { bf16x8 v[2]; __bf16 e[16]; } cv;
#pragma unroll
        for (int j = 0; j < 16; ++j) cv.e[j] = (__bf16)(Ts[ks + j][n] * scale);
        *(bf16x8*)&T[(size_t)(nt + n) * D + kt + ks] = cv.v[0];
        *(bf16x8*)&T[(size_t)(nt + n) * D + kt + ks + 8] = cv.v[1];
    }
}

// ---------- GEMM, C = A * B with Bt = B^T given ----------
// A [M,K] bf16 row stride lda (staged via global_load_lds), Bt [N,K] bf16
// row-major (stride K), C [M,N] row stride ldc (bf16 if OUTBF else f32).
// 128x128 tile, BK=32, 4 waves, each wave 64x64 (4x4 fragments of 16x16x32).
// 1D grid, bijective XCD-chunk swizzle (requires gridDim.x % 8 == 0).
template <int OUTBF>
__global__ __launch_bounds__(256) void gemm_bt(const unsigned short* __restrict__ A,
                                               const unsigned short* __restrict__ Bt,
                                               void* __restrict__ Cout,
                                               int M, int N, int K, int lda, int ldc,
                                               int nbx) {
    __shared__ __align__(16) unsigned short Au[128 * 32];
    __shared__ __align__(16) unsigned short Bs[128 * 32];
    const int tid = threadIdx.x;
    const int w = tid >> 6;
    const int lane = tid & 63;

    const int nwg = gridDim.x;
    const int q8 = nwg >> 3;
    const int orig = blockIdx.x;
    const int newlin = (orig & 7) * q8 + (orig >> 3);
    const int by = newlin / nbx;
    const int bx = newlin - by * nbx;
    const int m0 = by * 128;
    const int n0 = bx * 128;
    const int wr = w >> 1, wc = w & 1;

    f32x4 acc[4][4];
#pragma unroll
    for (int i = 0; i < 4; ++i)
#pragma unroll
        for (int j = 0; j < 4; ++j) acc[i][j] = f32x4{0.f, 0.f, 0.f, 0.f};

    for (int kt = 0; kt < K; kt += 32) {
#pragma unroll
        for (int p = 0; p < 2; ++p) {
            int c = p * 4 + w;
            int row = c * 16 + (lane >> 2);
            gload_lds16(A + (size_t)(m0 + row) * lda + kt + (lane & 3) * 8,
                        &Au[c * 512]);
        }
#pragma unroll
        for (int p = 0; p < 2; ++p) {
            int c = p * 4 + w;
            int row = c * 16 + (lane >> 2);
            gload_lds16(Bt + (size_t)(n0 + row) * K + kt + (lane & 3) * 8,
                        &Bs[c * 512]);
        }
        __syncthreads();

        bf16x8 af[4], bfr[4];
#pragma unroll
        for (int m = 0; m < 4; ++m)
            af[m] = *(const bf16x8*)&Au[(wr * 64 + m * 16 + (lane & 15)) * 32 +
                                        (lane >> 4) * 8];
#pragma unroll
        for (int n = 0; n < 4; ++n)
            bfr[n] = *(const bf16x8*)&Bs[(wc * 64 + n * 16 + (lane & 15)) * 32 +
                                         (lane >> 4) * 8];
#pragma unroll
        for (int m = 0; m < 4; ++m)
#pragma unroll
            for (int n = 0; n < 4; ++n)
                acc[m][n] = __builtin_amdgcn_mfma_f32_16x16x32_bf16(af[m], bfr[n], acc[m][n], 0, 0, 0);
        __syncthreads();
    }

    const int crow = (lane >> 4) * 4;
    const int ccol = lane & 15;
#pragma unroll
    for (int m = 0; m < 4; ++m) {
#pragma unroll
        for (int n = 0; n < 4; ++n) {
            int r0 = m0 + wr * 64 + m * 16 + crow;
            int c0 = n0 + wc * 64 + n * 16 + ccol;
#pragma unroll
            for (int j = 0; j < 4; ++j) {
                if (OUTBF)
                    ((unsigned short*)Cout)[(size_t)(r0 + j) * ldc + c0] = f2bf(acc[m][n][j]);
                else
                    ((float*)Cout)[(size_t)(r0 + j) * ldc + c0] = acc[m][n][j];
            }
        }
    }
}

// ---------- causal flash attention (round-7 version, verbatim) ----------
// QKV fused [B*L, 3072] bf16: Q cols [0,1024), K [1024,2048), V [2048,3072).
// Q pre-scaled by log2(e)/sqrt(hd). O written in-place over Q columns.
// Grid (32 bh, 32 qblk): linear%8 = bh%8 -> one head per XCD L2.
// y -> qblk 31-y: heavy blocks dispatch first.
// Ps layout [q][kv] with stride 72 (pad 8): per quarter-wave every Ps op is
// bank = 4*qi + const -> 2-way max (free). No XOR on Ps (r6 lesson).
__global__ __launch_bounds__(256) void flash_kernel(unsigned short* __restrict__ QKV) {
    __shared__ __align__(16) unsigned short Ks[2][64 * 72];   // [kv][d], +8 pad
    __shared__ __align__(16) unsigned short Vs[2][64 * 72];   // [d][kv], kv XOR-swizzled
    __shared__ __align__(16) unsigned short Ps[4][16 * 72];   // per-wave P^T as [q][kv]

    const int tid = threadIdx.x;
    const int w = tid >> 6;
    const int lane = tid & 63;
    const int bh = blockIdx.x;          // 0..31 ; XCD = bh % 8
    const int b = bh >> 4, h = bh & 15;
    const int rowbase = b * 2048;
    const int hd0 = h * 64;
    const int S = 3072;

    const int sr = tid >> 3;            // staging: K/V rows {p*32+sr}
    const int sc = (tid & 7) * 8;       //          cols [sc, sc+8)
    const int vswz = (tid & 7) << 3;    // V store column swizzle

    const int qi = lane & 15;           // this lane's q column (softmax space)
    const int g = lane >> 4;            // lane group

    const int qblk = (31 - (int)blockIdx.y) * 64;
    const int q0 = qblk + w * 16;
    const int nt = qblk / 64 + 1;
    const int q_rel = w * 16 + qi;      // q - qblk

    // Q fragments (B-operand), 2 d-steps of 32 over hd=64
    bf16x8 qf[2];
#pragma unroll
    for (int st = 0; st < 2; ++st)
        qf[st] = *(const bf16x8*)(QKV + (size_t)(rowbase + q0 + qi) * S + hd0 +
                                  st * 32 + g * 8);

    float m_prev = -1e30f, lsum = 0.f;
    f32x4 oacc[4];
#pragma unroll
    for (int n = 0; n < 4; ++n) oacc[n] = f32x4{0.f, 0.f, 0.f, 0.f};

    bf16x8 kreg[2], vreg[2];
    // prologue: tile 0 -> regs -> buf0 ; tile 1 -> regs
#pragma unroll
    for (int p = 0; p < 2; ++p) {
        size_t gi = (size_t)(rowbase + p * 32 + sr) * S + hd0 + sc;
        kreg[p] = *(const bf16x8*)(QKV + gi + 1024);
        vreg[p] = *(const bf16x8*)(QKV + gi + 2048);
    }
#pragma unroll
    for (int p = 0; p < 2; ++p) {
        int r = p * 32 + sr;
        *(bf16x8*)&Ks[0][r * 72 + sc] = kreg[p];
        int rs = r ^ vswz;
#pragma unroll
        for (int jj = 0; jj < 8; ++jj)
            Vs[0][(sc + jj) * 72 + rs] = ((const unsigned short*)&vreg[p])[jj];
    }
    if (nt > 1) {
#pragma unroll
        for (int p = 0; p < 2; ++p) {
            size_t gi = (size_t)(rowbase + 64 + p * 32 + sr) * S + hd0 + sc;
            kreg[p] = *(const bf16x8*)(QKV + gi + 1024);
            vreg[p] = *(const bf16x8*)(QKV + gi + 2048);
        }
    }
    __syncthreads();

    int cur = 0;
    for (int t = 0; t < nt; ++t) {
        // ---- write staged regs (tile t+1) to the other buffer; issue t+2 loads ----
        if (t + 1 < nt) {
#pragma unroll
            for (int p = 0; p < 2; ++p) {
                int r = p * 32 + sr;
                *(bf16x8*)&Ks[cur ^ 1][r * 72 + sc] = kreg[p];
                int rs = r ^ vswz;
#pragma unroll
                for (int jj = 0; jj < 8; ++jj)
                    Vs[cur ^ 1][(sc + jj) * 72 + rs] = ((const unsigned short*)&vreg[p])[jj];
            }
            if (t + 2 < nt) {
#pragma unroll
                for (int p = 0; p < 2; ++p) {
                    size_t gi = (size_t)(rowbase + (t + 2) * 64 + p * 32 + sr) * S + hd0 + sc;
                    kreg[p] = *(const bf16x8*)(QKV + gi + 1024);
                    vreg[p] = *(const bf16x8*)(QKV + gi + 2048);
                }
            }
        }

        const unsigned short* Kc = Ks[cur];
        const unsigned short* Vc = Vs[cur];

        // ---- S^T = K Q^T : sacc[n][j] = S[kv0 + n*16 + g*4 + j][q=qi] ----
        f32x4 sacc[4];
        __builtin_amdgcn_s_setprio(1);
#pragma unroll
        for (int n = 0; n < 4; ++n) {
            bf16x8 k0 = *(const bf16x8*)&Kc[(n * 16 + qi) * 72 + g * 8];
            bf16x8 k1 = *(const bf16x8*)&Kc[(n * 16 + qi) * 72 + 32 + g * 8];
            f32x4 c = f32x4{0.f, 0.f, 0.f, 0.f};
            c = __builtin_amdgcn_mfma_f32_16x16x32_bf16(k0, qf[0], c, 0, 0, 0);
            c = __builtin_amdgcn_mfma_f32_16x16x32_bf16(k1, qf[1], c, 0, 0, 0);
            sacc[n] = c;
        }
        __builtin_amdgcn_s_setprio(0);

        // ---- online softmax in exp2 domain (lane-local column q=qi) ----
        const bool diag = (t == nt - 1);
        if (diag) {
#pragma unroll
            for (int n = 0; n < 4; ++n)
#pragma unroll
                for (int j = 0; j < 4; ++j)
                    if (n * 16 + g * 4 + j > q_rel) sacc[n][j] = -1e30f;
        }
        float tmax = -1e30f;
#pragma unroll
        for (int n = 0; n < 4; ++n) {
            float a = fmaxf(fmaxf(sacc[n][0], sacc[n][1]), fmaxf(sacc[n][2], sacc[n][3]));
            tmax = fmaxf(tmax, a);
        }
        tmax = fmaxf(tmax, __shfl_xor(tmax, 16));
        tmax = fmaxf(tmax, __shfl_xor(tmax, 32));

        const bool defer = __all(tmax - m_prev <= 8.0f);
        const float mnew = defer ? m_prev : fmaxf(m_prev, tmax);

        float psum = 0.f;
#pragma unroll
        for (int n = 0; n < 4; ++n) {
            float p0 = exp2f(sacc[n][0] - mnew);
            float p1 = exp2f(sacc[n][1] - mnew);
            float p2 = exp2f(sacc[n][2] - mnew);
            float p3 = exp2f(sacc[n][3] - mnew);
            psum += (p0 + p1) + (p2 + p3);
            *(ushort4*)&Ps[w][qi * 72 + n * 16 + g * 4] = pack4bf(p0, p1, p2, p3);
        }
        psum += __shfl_xor(psum, 16);
        psum += __shfl_xor(psum, 32);
        if (!defer) {
            float alpha = exp2f(m_prev - mnew);
            lsum *= alpha;
#pragma unroll
            for (int n = 0; n < 4; ++n)
#pragma unroll
                for (int j = 0; j < 4; ++j) oacc[n][j] *= alpha;
            m_prev = mnew;
        }
        lsum += psum;

        // compile-time fence: Ps writes must precede the reads below
        asm volatile("" ::: "memory");

        // ---- O^T += V^T P^T ---- (DS ops complete in-order within a wave)
        __builtin_amdgcn_s_setprio(1);
#pragma unroll
        for (int st = 0; st < 2; ++st) {
            bf16x8 ptf = *(const bf16x8*)&Ps[w][qi * 72 + st * 32 + g * 8];
#pragma unroll
            for (int n = 0; n < 4; ++n) {
                int d = n * 16 + qi;
                int o = (st * 32 + g * 8) ^ (((d >> 3) & 7) << 3);
                bf16x8 vfr = *(const bf16x8*)&Vc[d * 72 + o];
                oacc[n] = __builtin_amdgcn_mfma_f32_16x16x32_bf16(vfr, ptf, oacc[n], 0, 0, 0);
            }
        }
        __builtin_amdgcn_s_setprio(0);
        __syncthreads();
        cur ^= 1;
    }

    // ---- normalize, transpose via Ps, coalesced O write over own Q rows ----
    {
        float inv = 1.0f / lsum;
#pragma unroll
        for (int n = 0; n < 4; ++n)
            *(ushort4*)&Ps[w][qi * 72 + n * 16 + g * 4] =
                pack4bf(oacc[n][0] * inv, oacc[n][1] * inv, oacc[n][2] * inv, oacc[n][3] * inv);
        asm volatile("" ::: "memory");
        const int r = lane >> 2;             // q row 0..15
        const int cs = (lane & 3) * 16;      // d start
        bf16x8 o0 = *(const bf16x8*)&Ps[w][r * 72 + cs];
        bf16x8 o1 = *(const bf16x8*)&Ps[w][r * 72 + cs + 8];
        *(bf16x8*)&QKV[(size_t)(rowbase + q0 + r) * S + hd0 + cs] = o0;
        *(bf16x8*)&QKV[(size_t)(rowbase + q0 + r) * S + hd0 + cs + 8] = o1;
    }
}

// ---------- launch ----------
extern "C" void kernel_launch(void* const* d_in, const int* in_sizes, int n_in,
                              void* d_out, int out_size, void* d_ws, size_t ws_size,
                              hipStream_t stream) {
    const float* x  = (const float*)d_in[0];
    const float* Wq = (const float*)d_in[1];
    const float* Wk = (const float*)d_in[2];
    const float* Wv = (const float*)d_in[3];
    const float* Wo = (const float*)d_in[4];
    float* out = (float*)d_out;

    const int WN = 1024 * 1024;
    const int XN = 4096 * 1024;

    // workspace: Wqkv_t [3072][1024] (6MB) + Wo_t (2MB) + QKV [4096][3072] (24MB) = 32MB.
    // x_bf16 (8MB) lives in d_out (16MB f32): consumed by the QKV GEMM, then
    // d_out is fully overwritten by the final O-projection. Deterministic.
    unsigned short* ws   = (unsigned short*)d_ws;
    unsigned short* Wqkv = ws;
    unsigned short* Wot  = Wqkv + 3 * WN;
    unsigned short* QKV  = Wot + WN;
    unsigned short* Xbf  = (unsigned short*)d_out;

    cast_x_kernel<<<XN / 1024, 256, 0, stream>>>(x, Xbf);

    // Q scale: 1/sqrt(64) * log2(e)  (softmax in exp2 domain)
    transpose4_kernel<<<dim3(16, 16, 4), 256, 0, stream>>>(
        Wq, Wk, Wv, Wo, Wqkv, Wqkv + WN, Wqkv + 2 * WN, Wot, 0.125f * 1.4426950408889634f);

    // fused QKV projection: [4096,1024] x [1024,3072] -> [4096,3072] (bf16 A path)
    gemm_bt<1><<<24 * 32, 256, 0, stream>>>(
        Xbf, Wqkv, QKV, 4096, 3072, 1024, 1024, 3072, 24);

    flash_kernel<<<dim3(32, 32), 256, 0, stream>>>(QKV);

    // output projection: A = O (bf16, Q region of QKV, lda=3072)
    gemm_bt<0><<<8 * 32, 256, 0, stream>>>(
        QKV, Wot, out, 4096, 1024, 1024, 3072, 1024, 8);
}